// Round 17
// baseline (94.718 us; speedup 1.0000x reference)
//
#include <hip/hip_runtime.h>

#define N_NODES 100000
#define N_EDGES 1000000
#define N_GRAPHS 512
#define VOCAB 10000
#define DIM 64

#define NPB 64                                // nodes per bucket (dst>>6)
#define NB 1563                               // ceil(N_NODES/NPB)
#define EPB 4096                              // edges per hist/scatter block
#define SB 245                                // ceil(N_EDGES/EPB)
#define BUILD_BLOCKS 625                      // 2500 waves x 4 rows = 10000 rows
#define CAP 1152                              // LDS sorted-list capacity (mean 640)

typedef unsigned short ushort_t;

// f32 -> bf16 round-to-nearest-even
static __device__ __forceinline__ ushort_t f2bf(float f) {
    unsigned u = __float_as_uint(f);
    unsigned r = 0x7FFFu + ((u >> 16) & 1u);
    return (ushort_t)((u + r) >> 16);
}
// pack two f32 -> u32 of two bf16 (lo, hi)
static __device__ __forceinline__ unsigned pk2bf(float lo, float hi) {
    return (unsigned)f2bf(lo) | ((unsigned)f2bf(hi) << 16);
}
#define BFLO(u) __uint_as_float((u) << 16)
#define BFHI(u) __uint_as_float((u) & 0xFFFF0000u)

// ---------------------------------------------------------------------------
// Kernel 1 (fused): blocks [0,SB) = bucket histogram (LDS atomics) + payload
// precompute + g_sum zero; blocks [SB,SB+BUILD_BLOCKS) = bf16 tables.
// Build branch v2: one wave owns 4 embed rows and emits ALL FOUR tables from
// a single e4 load + shfl set (4x fewer shfls and embed reads than v1).
__global__ __launch_bounds__(256)
void hist_build(const int* __restrict__ src,
                const int* __restrict__ dst,
                const int* __restrict__ etype,
                const int* __restrict__ x,
                int* __restrict__ bh,
                unsigned* __restrict__ payload,
                float* __restrict__ g_sum,
                const float* __restrict__ embed,
                const float* __restrict__ W_rel,
                const float* __restrict__ W_root,
                ushort_t* __restrict__ Tb) {
    if (blockIdx.x < SB) {
        // --- bucket histogram + payload ---
        for (int i = blockIdx.x * 256 + threadIdx.x; i < N_GRAPHS * DIM; i += SB * 256)
            g_sum[i] = 0.f;
        __shared__ int h[NB];
        for (int i = threadIdx.x; i < NB; i += 256) h[i] = 0;
        __syncthreads();
        int base = blockIdx.x * EPB;
        int lim  = base + EPB; if (lim > N_EDGES) lim = N_EDGES;
        for (int e = base + threadIdx.x; e < lim; e += 256) {
            int d = dst[e];
            atomicAdd(&h[d >> 6], 1);                    // LDS atomic
            payload[e] = ((unsigned)x[src[e]] << 8)
                       | ((unsigned)(d & 63) << 2)
                       | (unsigned)etype[e];
        }
        __syncthreads();
        for (int i = threadIdx.x; i < NB; i += 256)
            bh[blockIdx.x * NB + i] = h[i];              // block-major: coalesced
    } else {
        // --- build all 4 tables per wave: 4 rows, one e4 load + shfl set ---
        int tid  = (blockIdx.x - SB) * 256 + threadIdx.x;
        int l    = tid & 63;
        int wave = tid >> 6;              // 0..2499
        int sub  = l >> 4;                // row-within-wave 0..3
        int q    = l & 15;                // feature quad
        int v    = wave * 4 + sub;        // embed row 0..9999
        float4 e4  = *(const float4*)(embed + (size_t)v * DIM + q * 4);
        float4 acc0 = {0.f, 0.f, 0.f, 0.f};   // root
        float4 acc1 = {0.f, 0.f, 0.f, 0.f};   // rel 0
        float4 acc2 = {0.f, 0.f, 0.f, 0.f};   // rel 1
        float4 acc3 = {0.f, 0.f, 0.f, 0.f};   // rel 2
#pragma unroll
        for (int kk = 0; kk < 16; ++kk) {
            int srcl = sub * 16 + kk;
            float ex = __shfl(e4.x, srcl, 64);
            float ey = __shfl(e4.y, srcl, 64);
            float ez = __shfl(e4.z, srcl, 64);
            float ew = __shfl(e4.w, srcl, 64);
#pragma unroll
            for (int m = 0; m < 4; ++m) {
                const float* W = (m == 0) ? W_root
                                          : (W_rel + (size_t)(m - 1) * DIM * DIM);
                const float4 w0 = *(const float4*)(W + (4 * kk + 0) * DIM + q * 4);
                const float4 w1 = *(const float4*)(W + (4 * kk + 1) * DIM + q * 4);
                const float4 w2 = *(const float4*)(W + (4 * kk + 2) * DIM + q * 4);
                const float4 w3 = *(const float4*)(W + (4 * kk + 3) * DIM + q * 4);
                float4* ac = (m == 0) ? &acc0 : (m == 1) ? &acc1 : (m == 2) ? &acc2 : &acc3;
                ac->x += ex * w0.x; ac->y += ex * w0.y; ac->z += ex * w0.z; ac->w += ex * w0.w;
                ac->x += ey * w1.x; ac->y += ey * w1.y; ac->z += ey * w1.z; ac->w += ey * w1.w;
                ac->x += ez * w2.x; ac->y += ez * w2.y; ac->z += ez * w2.z; ac->w += ez * w2.w;
                ac->x += ew * w3.x; ac->y += ew * w3.y; ac->z += ew * w3.z; ac->w += ew * w3.w;
            }
        }
        // packed 2xbf16 stores: 2 u32 per table
        unsigned* p0 = (unsigned*)(Tb + ((size_t)0 * VOCAB + v) * DIM + q * 4);
        unsigned* p1 = (unsigned*)(Tb + ((size_t)1 * VOCAB + v) * DIM + q * 4);
        unsigned* p2 = (unsigned*)(Tb + ((size_t)2 * VOCAB + v) * DIM + q * 4);
        unsigned* p3 = (unsigned*)(Tb + ((size_t)3 * VOCAB + v) * DIM + q * 4);
        p0[0] = pk2bf(acc0.x, acc0.y); p0[1] = pk2bf(acc0.z, acc0.w);
        p1[0] = pk2bf(acc1.x, acc1.y); p1[1] = pk2bf(acc1.z, acc1.w);
        p2[0] = pk2bf(acc2.x, acc2.y); p2[1] = pk2bf(acc2.z, acc2.w);
        p3[0] = pk2bf(acc3.x, acc3.y); p3[1] = pk2bf(acc3.z, acc3.w);
    }
}

// ---------------------------------------------------------------------------
// Kernel 2: per-bucket row scan. Block b scans bh[j][b] over j=0..SB ->
// loc[b][j] (coalesced write) and bucket total btot[b].
__global__ __launch_bounds__(256)
void rowscan(const int* __restrict__ bh, int* __restrict__ loc,
             int* __restrict__ btot) {
    __shared__ int wsum4[4];
    int b = blockIdx.x, t = threadIdx.x;
    int l = t & 63, wv = t >> 6;
    int v = (t < SB) ? bh[t * NB + b] : 0;     // strided read (L2-resident)
    int sc = v;
#pragma unroll
    for (int d = 1; d < 64; d <<= 1) {
        int tt = __shfl_up(sc, d, 64);
        if (l >= d) sc += tt;
    }
    if (l == 63) wsum4[wv] = sc;
    __syncthreads();
    if (t == 0) {
        int a = 0;
#pragma unroll
        for (int k = 0; k < 4; ++k) { int tmp = wsum4[k]; wsum4[k] = a; a += tmp; }
    }
    __syncthreads();
    int excl = sc - v + wsum4[wv];
    if (t < SB) loc[b * SB + t] = excl;
    if (t == 255) btot[b] = excl;          // v==0 at t=255 -> excl == total
}

// ---------------------------------------------------------------------------
// Kernel 3: bucket scatter (1024 threads) with INLINE btot scan.
// Each block scans btot -> baseh in LDS; block 0 publishes bbase for the
// next kernel; then adds its loc column and scatters records.
__global__ __launch_bounds__(1024)
void bucket_scatter(const int* __restrict__ dst,
                    const unsigned* __restrict__ payload,
                    const int* __restrict__ loc,
                    const int* __restrict__ btot,
                    int* __restrict__ bbase,
                    unsigned* __restrict__ rec) {
    __shared__ int wsum16[16];
    __shared__ int baseh[NB];
    __shared__ int h[NB];
    int t = threadIdx.x;
    int l = t & 63, wv = t >> 6;

    // ---- in-block exclusive scan of btot[0..NB) (2 elems/thread) ----
    int v0 = (2 * t + 0 < NB) ? btot[2 * t + 0] : 0;
    int v1 = (2 * t + 1 < NB) ? btot[2 * t + 1] : 0;
    int lsum = v0 + v1;
    int sc = lsum;
#pragma unroll
    for (int d = 1; d < 64; d <<= 1) {
        int tt = __shfl_up(sc, d, 64);
        if (l >= d) sc += tt;
    }
    if (l == 63) wsum16[wv] = sc;
    __syncthreads();
    if (t == 0) {
        int a = 0;
#pragma unroll
        for (int k = 0; k < 16; ++k) { int tmp = wsum16[k]; wsum16[k] = a; a += tmp; }
    }
    __syncthreads();
    int p = sc - lsum + wsum16[wv];
    if (2 * t + 0 < NB) baseh[2 * t + 0] = p; p += v0;
    if (2 * t + 1 < NB) baseh[2 * t + 1] = p;
    __syncthreads();

    // block 0 publishes bbase (pure btot scan) for sort_aggregate
    if (blockIdx.x == 0) {
        for (int i = t; i < NB; i += 1024) bbase[i] = baseh[i];
        if (t == 0) bbase[NB] = N_EDGES;
    }
    // add this block's loc column; zero cursors
    for (int i = t; i < NB; i += 1024) {
        baseh[i] += loc[i * SB + blockIdx.x];
        h[i] = 0;
    }
    __syncthreads();

    // ---- scatter (payload precomputed; no gathers here) ----
    int base = blockIdx.x * EPB;
    int lim  = base + EPB; if (lim > N_EDGES) lim = N_EDGES;
    for (int e = base + t; e < lim; e += 1024) {
        int b = dst[e] >> 6;
        int rk = atomicAdd(&h[b], 1);                // LDS returning atomic
        rec[baseh[b] + rk] = payload[e];
    }
}

// ---------------------------------------------------------------------------
// Kernel 4 (fused sort + aggregate + pool): block per bucket.
__global__ __launch_bounds__(256)
void sort_aggregate(const int* __restrict__ x,
                    const int* __restrict__ batch,
                    const int* __restrict__ bbase,
                    const unsigned* __restrict__ rec,
                    const ushort_t* __restrict__ Tb,
                    const float* __restrict__ bias,
                    float* __restrict__ g_sum) {
    __shared__ int cstart[257];
    __shared__ int cur[256];
    __shared__ int wsum4[4];
    __shared__ float inv_sh[256];
    __shared__ unsigned sortedc[CAP];
    __shared__ float rows[NPB * DIM];     // 16 KB node-output rows
    __shared__ float red[256];
    __shared__ int batch_sh[NPB];
    int b = blockIdx.x, t = threadIdx.x;
    int s = bbase[b];
    int e = bbase[b + 1];
    int ne = e - s;
    int nvalid = N_NODES - b * NPB; if (nvalid > NPB) nvalid = NPB;

    cstart[t] = 0;
    if (t < NPB) batch_sh[t] = (t < nvalid) ? batch[b * NPB + t] : -1;
    __syncthreads();
    // phase 1a: count keys (key = low 8 payload bits)
    for (int i = t; i < ne; i += 256)
        atomicAdd(&cstart[rec[s + i] & 0xFFu], 1);
    __syncthreads();
    // phase 1b: 256-wide exclusive scan of counts
    {
        int l = t & 63, wv = t >> 6;
        int v = cstart[t];
        int sc = v;
#pragma unroll
        for (int d = 1; d < 64; d <<= 1) {
            int tt = __shfl_up(sc, d, 64);
            if (l >= d) sc += tt;
        }
        if (l == 63) wsum4[wv] = sc;
        __syncthreads();
        if (t == 0) {
            int a = 0;
#pragma unroll
            for (int k = 0; k < 4; ++k) { int tmp = wsum4[k]; wsum4[k] = a; a += tmp; }
        }
        __syncthreads();
        int excl = sc - v + wsum4[wv];
        __syncthreads();            // cstart reads done; safe to overwrite
        cstart[t] = excl;
        cur[t] = excl;
        if (t == 255) cstart[256] = excl + v;
    }
    __syncthreads();
    // per-key inverse counts
    inv_sh[t] = 1.f / fmaxf((float)(cstart[t + 1] - cstart[t]), 1.f);
    // phase 1c: place records in (node,rel) order (record IS the combo)
    for (int i = t; i < ne; i += 256) {
        unsigned p = rec[s + i];
        int rk = atomicAdd(&cur[p & 0xFFu], 1);
        sortedc[rk] = p;
    }
    __syncthreads();

    // phase 2: gather-aggregate. group = t>>3 (0..31), sl = t&7.
    int grp = t >> 3;
    int sl  = t & 7;
    const ushort_t* TbRel = Tb + (size_t)VOCAB * DIM;   // relation tables base
#pragma unroll
    for (int nn = 0; nn < 2; ++nn) {
        int n = grp * 2 + nn;
        if (n >= nvalid) continue;
        int node = b * NPB + n;
        int i0 = cstart[n << 2];
        int i1 = cstart[(n + 1) << 2];
        float a0 = 0.f, a1 = 0.f, a2 = 0.f, a3 = 0.f,
              a4 = 0.f, a5 = 0.f, a6 = 0.f, a7 = 0.f;
        int i = i0;
        for (; i + 4 <= i1; i += 4) {                  // 4 gathers in flight
            unsigned c1 = sortedc[i],     c2 = sortedc[i + 1];
            unsigned c3 = sortedc[i + 2], c4 = sortedc[i + 3];
            const uint4 t1 = *(const uint4*)(TbRel +
                ((size_t)(c1 & 3u) * VOCAB + (c1 >> 8)) * DIM + sl * 8);
            const uint4 t2 = *(const uint4*)(TbRel +
                ((size_t)(c2 & 3u) * VOCAB + (c2 >> 8)) * DIM + sl * 8);
            const uint4 t3 = *(const uint4*)(TbRel +
                ((size_t)(c3 & 3u) * VOCAB + (c3 >> 8)) * DIM + sl * 8);
            const uint4 t4 = *(const uint4*)(TbRel +
                ((size_t)(c4 & 3u) * VOCAB + (c4 >> 8)) * DIM + sl * 8);
            float iv1 = inv_sh[c1 & 0xFFu], iv2 = inv_sh[c2 & 0xFFu];
            float iv3 = inv_sh[c3 & 0xFFu], iv4 = inv_sh[c4 & 0xFFu];
            a0 += BFLO(t1.x) * iv1; a1 += BFHI(t1.x) * iv1;
            a2 += BFLO(t1.y) * iv1; a3 += BFHI(t1.y) * iv1;
            a4 += BFLO(t1.z) * iv1; a5 += BFHI(t1.z) * iv1;
            a6 += BFLO(t1.w) * iv1; a7 += BFHI(t1.w) * iv1;
            a0 += BFLO(t2.x) * iv2; a1 += BFHI(t2.x) * iv2;
            a2 += BFLO(t2.y) * iv2; a3 += BFHI(t2.y) * iv2;
            a4 += BFLO(t2.z) * iv2; a5 += BFHI(t2.z) * iv2;
            a6 += BFLO(t2.w) * iv2; a7 += BFHI(t2.w) * iv2;
            a0 += BFLO(t3.x) * iv3; a1 += BFHI(t3.x) * iv3;
            a2 += BFLO(t3.y) * iv3; a3 += BFHI(t3.y) * iv3;
            a4 += BFLO(t3.z) * iv3; a5 += BFHI(t3.z) * iv3;
            a6 += BFLO(t3.w) * iv3; a7 += BFHI(t3.w) * iv3;
            a0 += BFLO(t4.x) * iv4; a1 += BFHI(t4.x) * iv4;
            a2 += BFLO(t4.y) * iv4; a3 += BFHI(t4.y) * iv4;
            a4 += BFLO(t4.z) * iv4; a5 += BFHI(t4.z) * iv4;
            a6 += BFLO(t4.w) * iv4; a7 += BFHI(t4.w) * iv4;
        }
        for (; i < i1; ++i) {                           // tail edges
            unsigned c1 = sortedc[i];
            const uint4 t1 = *(const uint4*)(TbRel +
                ((size_t)(c1 & 3u) * VOCAB + (c1 >> 8)) * DIM + sl * 8);
            float iv1 = inv_sh[c1 & 0xFFu];
            a0 += BFLO(t1.x) * iv1; a1 += BFHI(t1.x) * iv1;
            a2 += BFLO(t1.y) * iv1; a3 += BFHI(t1.y) * iv1;
            a4 += BFLO(t1.z) * iv1; a5 += BFHI(t1.z) * iv1;
            a6 += BFLO(t1.w) * iv1; a7 += BFHI(t1.w) * iv1;
        }
        // root + bias + ReLU -> LDS rows
        int xv = x[node];
        const uint4 rt = *(const uint4*)(Tb + (size_t)xv * DIM + sl * 8);
        const float4 b0 = *(const float4*)(bias + sl * 8);
        const float4 b1 = *(const float4*)(bias + sl * 8 + 4);
        float* rp = rows + n * DIM + sl * 8;
        rp[0] = fmaxf(BFLO(rt.x) + b0.x + a0, 0.f);
        rp[1] = fmaxf(BFHI(rt.x) + b0.y + a1, 0.f);
        rp[2] = fmaxf(BFLO(rt.y) + b0.z + a2, 0.f);
        rp[3] = fmaxf(BFHI(rt.y) + b0.w + a3, 0.f);
        rp[4] = fmaxf(BFLO(rt.z) + b1.x + a4, 0.f);
        rp[5] = fmaxf(BFHI(rt.z) + b1.y + a5, 0.f);
        rp[6] = fmaxf(BFLO(rt.w) + b1.z + a6, 0.f);
        rp[7] = fmaxf(BFHI(rt.w) + b1.w + a7, 0.f);
    }
    __syncthreads();

    // phase 3: per-graph pooling reduce (batch sorted: few graphs/bucket).
    int gmin = batch_sh[0];
    int gmax = batch_sh[nvalid - 1];
    int f  = t & 63;                    // feature
    int n0 = t >> 6;                    // 4-thread stride over nodes
    for (int g = gmin; g <= gmax; ++g) {
        float a = 0.f;
        for (int n = n0; n < nvalid; n += 4)
            a += (batch_sh[n] == g) ? rows[n * DIM + f] : 0.f;
        red[t] = a;
        __syncthreads();
        if (t < 64) {
            float tot = red[t] + red[t + 64] + red[t + 128] + red[t + 192];
            if (tot != 0.f) atomicAdd(&g_sum[g * DIM + t], tot);
        }
        __syncthreads();
    }
}

// ---------------------------------------------------------------------------
// Kernel 5: per-graph mean + 64->2 linear. 512 blocks x 64 lanes.
__device__ __forceinline__ int lbound(const int* __restrict__ b, int val) {
    int lo = 0, hi = N_NODES;
    while (lo < hi) {
        int mid = (lo + hi) >> 1;
        if (b[mid] < val) lo = mid + 1; else hi = mid;
    }
    return lo;
}

__global__ __launch_bounds__(64)
void final_linear(const int* __restrict__ batch,
                  const float* __restrict__ g_sum,
                  const float* __restrict__ lin_W,
                  const float* __restrict__ lin_b,
                  float* __restrict__ out) {
    int g = blockIdx.x;
    int l = threadIdx.x;   // 0..63
    int s = lbound(batch, g);
    int e = lbound(batch, g + 1);
    float mean = (e > s) ? g_sum[g * DIM + l] / (float)(e - s) : 0.f;
    float p0 = mean * lin_W[l * 2 + 0];
    float p1 = mean * lin_W[l * 2 + 1];
#pragma unroll
    for (int off2 = 32; off2 > 0; off2 >>= 1) {
        p0 += __shfl_down(p0, off2, 64);
        p1 += __shfl_down(p1, off2, 64);
    }
    if (l == 0) {
        out[g * 2 + 0] = p0 + lin_b[0];
        out[g * 2 + 1] = p1 + lin_b[1];
    }
}

// ---------------------------------------------------------------------------
extern "C" void kernel_launch(void* const* d_in, const int* in_sizes, int n_in,
                              void* d_out, int out_size, void* d_ws, size_t ws_size,
                              hipStream_t stream) {
    const int*   x      = (const int*)d_in[0];
    const int*   eidx   = (const int*)d_in[1];   // [2, E]
    const int*   etype  = (const int*)d_in[2];
    const int*   batch  = (const int*)d_in[3];
    const float* embed  = (const float*)d_in[4];
    const float* W_rel  = (const float*)d_in[5];
    const float* W_root = (const float*)d_in[6];
    const float* bias   = (const float*)d_in[7];
    const float* lin_W  = (const float*)d_in[8];
    const float* lin_b  = (const float*)d_in[9];
    float* out = (float*)d_out;

    const int* src = eidx;
    const int* dst = eidx + N_EDGES;

    // Workspace layout (bytes). No memsets (g_sum zeroed in hist_build).
    //   Tb      : 4*VOCAB*64*2 = 5,120,000   at          0
    //   rec     : 1M*4         = 4,000,000   at  5,120,000
    //   payload : 1M*4         = 4,000,000   at  9,120,000
    //   loc     : NB*SB*4      = 1,531,740   at 13,120,000
    //   btot    : NB*4         =     6,252   at 14,651,776
    //   bbase   : (NB+1)*4     =     6,256   at 14,658,048
    //   bh      : NB*SB*4      = 1,531,740   at 14,664,320
    //   g_sum   : 512*64*4     =   131,072   at 16,196,096
    char* ws = (char*)d_ws;
    ushort_t* Tb      = (ushort_t*)(ws);
    unsigned* rec     = (unsigned*)(ws + 5120000);
    unsigned* payload = (unsigned*)(ws + 9120000);
    int* loc          = (int*)(ws + 13120000);
    int* btot         = (int*)(ws + 14651776);
    int* bbase        = (int*)(ws + 14658048);
    int* bh           = (int*)(ws + 14664320);
    float* g_sum      = (float*)(ws + 16196096);

    // 1. fused: bucket histogram + payload (+g_sum zero)  ||  bf16 table build
    hist_build<<<SB + BUILD_BLOCKS, 256, 0, stream>>>(
        src, dst, etype, x, bh, payload, g_sum, embed, W_rel, W_root, Tb);

    // 2. per-bucket row scan -> loc, btot
    rowscan<<<NB, 256, 0, stream>>>(bh, loc, btot);

    // 3. bucket scatter with inline btot scan (block 0 publishes bbase)
    bucket_scatter<<<SB, 1024, 0, stream>>>(dst, payload, loc, btot, bbase, rec);

    // 4. fused LDS sort + aggregation + pooling
    sort_aggregate<<<NB, 256, 0, stream>>>(x, batch, bbase, rec, Tb, bias, g_sum);

    // 5. per-graph mean + linear
    final_linear<<<N_GRAPHS, 64, 0, stream>>>(batch, g_sum, lin_W, lin_b, out);
}

// Round 18
// 81.779 us; speedup vs baseline: 1.1582x; 1.1582x over previous
//
#include <hip/hip_runtime.h>

#define N_NODES 100000
#define N_EDGES 1000000
#define N_GRAPHS 512
#define VOCAB 10000
#define DIM 64

#define NPB 64                                // nodes per bucket (dst>>6)
#define NB 1563                               // ceil(N_NODES/NPB)
#define EPB 4096                              // edges per hist/scatter block
#define SB 245                                // ceil(N_EDGES/EPB)
#define BUILD_BLOCKS ((4 * VOCAB) / 16)       // 2500 blocks x 256 thr
#define CAP 1152                              // LDS sorted-list capacity (mean 640)

typedef unsigned short ushort_t;

// f32 -> bf16 round-to-nearest-even
static __device__ __forceinline__ ushort_t f2bf(float f) {
    unsigned u = __float_as_uint(f);
    unsigned r = 0x7FFFu + ((u >> 16) & 1u);
    return (ushort_t)((u + r) >> 16);
}
// pack two f32 -> u32 of two bf16 (lo, hi)
static __device__ __forceinline__ unsigned pk2bf(float lo, float hi) {
    return (unsigned)f2bf(lo) | ((unsigned)f2bf(hi) << 16);
}
#define BFLO(u) __uint_as_float((u) << 16)
#define BFHI(u) __uint_as_float((u) & 0xFFFF0000u)

// ---------------------------------------------------------------------------
// Kernel 1 (fused): blocks [0,SB) = bucket histogram (LDS atomics) + payload
// precompute + g_sum zero; blocks [SB,SB+BUILD_BLOCKS) = bf16 tables.
// (round-15 proven structure; only the table stores are packed u32 now)
__global__ __launch_bounds__(256)
void hist_build(const int* __restrict__ src,
                const int* __restrict__ dst,
                const int* __restrict__ etype,
                const int* __restrict__ x,
                int* __restrict__ bh,
                unsigned* __restrict__ payload,
                float* __restrict__ g_sum,
                const float* __restrict__ embed,
                const float* __restrict__ W_rel,
                const float* __restrict__ W_root,
                ushort_t* __restrict__ Tb) {
    if (blockIdx.x < SB) {
        // --- bucket histogram + payload ---
        for (int i = blockIdx.x * 256 + threadIdx.x; i < N_GRAPHS * DIM; i += SB * 256)
            g_sum[i] = 0.f;
        __shared__ int h[NB];
        for (int i = threadIdx.x; i < NB; i += 256) h[i] = 0;
        __syncthreads();
        int base = blockIdx.x * EPB;
        int lim  = base + EPB; if (lim > N_EDGES) lim = N_EDGES;
        for (int e = base + threadIdx.x; e < lim; e += 256) {
            int d = dst[e];
            atomicAdd(&h[d >> 6], 1);                    // LDS atomic
            payload[e] = ((unsigned)x[src[e]] << 8)
                       | ((unsigned)(d & 63) << 2)
                       | (unsigned)etype[e];
        }
        __syncthreads();
        for (int i = threadIdx.x; i < NB; i += 256)
            bh[blockIdx.x * NB + i] = h[i];              // block-major: coalesced
    } else {
        // --- build tables: 4 rows per wave; float4 math, packed bf16 store ---
        int tid  = (blockIdx.x - SB) * 256 + threadIdx.x;
        int l    = tid & 63;
        int wave = tid >> 6;              // 0..9999
        int sub  = l >> 4;                // row-within-wave 0..3
        int q    = l & 15;                // feature quad
        int row  = wave * 4 + sub;        // wave never crosses m (10000%4==0)
        int m    = row / VOCAB;
        int v    = row - m * VOCAB;
        const float* W = (m == 0) ? W_root : (W_rel + (size_t)(m - 1) * DIM * DIM);
        float4 e4  = *(const float4*)(embed + (size_t)v * DIM + q * 4);
        float4 acc = {0.f, 0.f, 0.f, 0.f};
#pragma unroll
        for (int kk = 0; kk < 16; ++kk) {
            int srcl = sub * 16 + kk;
            float ex = __shfl(e4.x, srcl, 64);
            float ey = __shfl(e4.y, srcl, 64);
            float ez = __shfl(e4.z, srcl, 64);
            float ew = __shfl(e4.w, srcl, 64);
            const float4 w0 = *(const float4*)(W + (4 * kk + 0) * DIM + q * 4);
            const float4 w1 = *(const float4*)(W + (4 * kk + 1) * DIM + q * 4);
            const float4 w2 = *(const float4*)(W + (4 * kk + 2) * DIM + q * 4);
            const float4 w3 = *(const float4*)(W + (4 * kk + 3) * DIM + q * 4);
            acc.x += ex * w0.x; acc.y += ex * w0.y; acc.z += ex * w0.z; acc.w += ex * w0.w;
            acc.x += ey * w1.x; acc.y += ey * w1.y; acc.z += ey * w1.z; acc.w += ey * w1.w;
            acc.x += ez * w2.x; acc.y += ez * w2.y; acc.z += ez * w2.z; acc.w += ez * w2.w;
            acc.x += ew * w3.x; acc.y += ew * w3.y; acc.z += ew * w3.z; acc.w += ew * w3.w;
        }
        unsigned* p = (unsigned*)(Tb + (size_t)row * DIM + q * 4);   // 4B-aligned
        p[0] = pk2bf(acc.x, acc.y);
        p[1] = pk2bf(acc.z, acc.w);
    }
}

// ---------------------------------------------------------------------------
// Kernel 2: per-bucket row scan. Block b scans bh[j][b] over j=0..SB ->
// loc[b][j] (coalesced write) and bucket total btot[b].
__global__ __launch_bounds__(256)
void rowscan(const int* __restrict__ bh, int* __restrict__ loc,
             int* __restrict__ btot) {
    __shared__ int wsum4[4];
    int b = blockIdx.x, t = threadIdx.x;
    int l = t & 63, wv = t >> 6;
    int v = (t < SB) ? bh[t * NB + b] : 0;     // strided read (L2-resident)
    int sc = v;
#pragma unroll
    for (int d = 1; d < 64; d <<= 1) {
        int tt = __shfl_up(sc, d, 64);
        if (l >= d) sc += tt;
    }
    if (l == 63) wsum4[wv] = sc;
    __syncthreads();
    if (t == 0) {
        int a = 0;
#pragma unroll
        for (int k = 0; k < 4; ++k) { int tmp = wsum4[k]; wsum4[k] = a; a += tmp; }
    }
    __syncthreads();
    int excl = sc - v + wsum4[wv];
    if (t < SB) loc[b * SB + t] = excl;
    if (t == 255) btot[b] = excl;          // v==0 at t=255 -> excl == total
}

// ---------------------------------------------------------------------------
// Kernel 3: bucket scatter (1024 threads) with INLINE btot scan.
// Each block scans btot -> baseh in LDS; block 0 publishes bbase for the
// next kernel; then adds its loc column and scatters records.
__global__ __launch_bounds__(1024)
void bucket_scatter(const int* __restrict__ dst,
                    const unsigned* __restrict__ payload,
                    const int* __restrict__ loc,
                    const int* __restrict__ btot,
                    int* __restrict__ bbase,
                    unsigned* __restrict__ rec) {
    __shared__ int wsum16[16];
    __shared__ int baseh[NB];
    __shared__ int h[NB];
    int t = threadIdx.x;
    int l = t & 63, wv = t >> 6;

    // ---- in-block exclusive scan of btot[0..NB) (2 elems/thread) ----
    int v0 = (2 * t + 0 < NB) ? btot[2 * t + 0] : 0;
    int v1 = (2 * t + 1 < NB) ? btot[2 * t + 1] : 0;
    int lsum = v0 + v1;
    int sc = lsum;
#pragma unroll
    for (int d = 1; d < 64; d <<= 1) {
        int tt = __shfl_up(sc, d, 64);
        if (l >= d) sc += tt;
    }
    if (l == 63) wsum16[wv] = sc;
    __syncthreads();
    if (t == 0) {
        int a = 0;
#pragma unroll
        for (int k = 0; k < 16; ++k) { int tmp = wsum16[k]; wsum16[k] = a; a += tmp; }
    }
    __syncthreads();
    int p = sc - lsum + wsum16[wv];
    if (2 * t + 0 < NB) baseh[2 * t + 0] = p; p += v0;
    if (2 * t + 1 < NB) baseh[2 * t + 1] = p;
    __syncthreads();

    // block 0 publishes bbase (pure btot scan) for sort_aggregate
    if (blockIdx.x == 0) {
        for (int i = t; i < NB; i += 1024) bbase[i] = baseh[i];
        if (t == 0) bbase[NB] = N_EDGES;
    }
    // add this block's loc column; zero cursors
    for (int i = t; i < NB; i += 1024) {
        baseh[i] += loc[i * SB + blockIdx.x];
        h[i] = 0;
    }
    __syncthreads();

    // ---- scatter (payload precomputed; no gathers here) ----
    int base = blockIdx.x * EPB;
    int lim  = base + EPB; if (lim > N_EDGES) lim = N_EDGES;
    for (int e = base + t; e < lim; e += 1024) {
        int b = dst[e] >> 6;
        int rk = atomicAdd(&h[b], 1);                // LDS returning atomic
        rec[baseh[b] + rk] = payload[e];
    }
}

// ---------------------------------------------------------------------------
// Kernel 4 (fused sort + aggregate + pool): block per bucket.
__global__ __launch_bounds__(256)
void sort_aggregate(const int* __restrict__ x,
                    const int* __restrict__ batch,
                    const int* __restrict__ bbase,
                    const unsigned* __restrict__ rec,
                    const ushort_t* __restrict__ Tb,
                    const float* __restrict__ bias,
                    float* __restrict__ g_sum) {
    __shared__ int cstart[257];
    __shared__ int cur[256];
    __shared__ int wsum4[4];
    __shared__ float inv_sh[256];
    __shared__ unsigned sortedc[CAP];
    __shared__ float rows[NPB * DIM];     // 16 KB node-output rows
    __shared__ float red[256];
    __shared__ int batch_sh[NPB];
    int b = blockIdx.x, t = threadIdx.x;
    int s = bbase[b];
    int e = bbase[b + 1];
    int ne = e - s;
    int nvalid = N_NODES - b * NPB; if (nvalid > NPB) nvalid = NPB;

    cstart[t] = 0;
    if (t < NPB) batch_sh[t] = (t < nvalid) ? batch[b * NPB + t] : -1;
    __syncthreads();
    // phase 1a: count keys (key = low 8 payload bits)
    for (int i = t; i < ne; i += 256)
        atomicAdd(&cstart[rec[s + i] & 0xFFu], 1);
    __syncthreads();
    // phase 1b: 256-wide exclusive scan of counts
    {
        int l = t & 63, wv = t >> 6;
        int v = cstart[t];
        int sc = v;
#pragma unroll
        for (int d = 1; d < 64; d <<= 1) {
            int tt = __shfl_up(sc, d, 64);
            if (l >= d) sc += tt;
        }
        if (l == 63) wsum4[wv] = sc;
        __syncthreads();
        if (t == 0) {
            int a = 0;
#pragma unroll
            for (int k = 0; k < 4; ++k) { int tmp = wsum4[k]; wsum4[k] = a; a += tmp; }
        }
        __syncthreads();
        int excl = sc - v + wsum4[wv];
        __syncthreads();            // cstart reads done; safe to overwrite
        cstart[t] = excl;
        cur[t] = excl;
        if (t == 255) cstart[256] = excl + v;
    }
    __syncthreads();
    // per-key inverse counts
    inv_sh[t] = 1.f / fmaxf((float)(cstart[t + 1] - cstart[t]), 1.f);
    // phase 1c: place records in (node,rel) order (record IS the combo)
    for (int i = t; i < ne; i += 256) {
        unsigned p = rec[s + i];
        int rk = atomicAdd(&cur[p & 0xFFu], 1);
        sortedc[rk] = p;
    }
    __syncthreads();

    // phase 2: gather-aggregate. group = t>>3 (0..31), sl = t&7.
    int grp = t >> 3;
    int sl  = t & 7;
    const ushort_t* TbRel = Tb + (size_t)VOCAB * DIM;   // relation tables base
#pragma unroll
    for (int nn = 0; nn < 2; ++nn) {
        int n = grp * 2 + nn;
        if (n >= nvalid) continue;
        int node = b * NPB + n;
        int i0 = cstart[n << 2];
        int i1 = cstart[(n + 1) << 2];
        float a0 = 0.f, a1 = 0.f, a2 = 0.f, a3 = 0.f,
              a4 = 0.f, a5 = 0.f, a6 = 0.f, a7 = 0.f;
        int i = i0;
        for (; i + 4 <= i1; i += 4) {                  // 4 gathers in flight
            unsigned c1 = sortedc[i],     c2 = sortedc[i + 1];
            unsigned c3 = sortedc[i + 2], c4 = sortedc[i + 3];
            const uint4 t1 = *(const uint4*)(TbRel +
                ((size_t)(c1 & 3u) * VOCAB + (c1 >> 8)) * DIM + sl * 8);
            const uint4 t2 = *(const uint4*)(TbRel +
                ((size_t)(c2 & 3u) * VOCAB + (c2 >> 8)) * DIM + sl * 8);
            const uint4 t3 = *(const uint4*)(TbRel +
                ((size_t)(c3 & 3u) * VOCAB + (c3 >> 8)) * DIM + sl * 8);
            const uint4 t4 = *(const uint4*)(TbRel +
                ((size_t)(c4 & 3u) * VOCAB + (c4 >> 8)) * DIM + sl * 8);
            float iv1 = inv_sh[c1 & 0xFFu], iv2 = inv_sh[c2 & 0xFFu];
            float iv3 = inv_sh[c3 & 0xFFu], iv4 = inv_sh[c4 & 0xFFu];
            a0 += BFLO(t1.x) * iv1; a1 += BFHI(t1.x) * iv1;
            a2 += BFLO(t1.y) * iv1; a3 += BFHI(t1.y) * iv1;
            a4 += BFLO(t1.z) * iv1; a5 += BFHI(t1.z) * iv1;
            a6 += BFLO(t1.w) * iv1; a7 += BFHI(t1.w) * iv1;
            a0 += BFLO(t2.x) * iv2; a1 += BFHI(t2.x) * iv2;
            a2 += BFLO(t2.y) * iv2; a3 += BFHI(t2.y) * iv2;
            a4 += BFLO(t2.z) * iv2; a5 += BFHI(t2.z) * iv2;
            a6 += BFLO(t2.w) * iv2; a7 += BFHI(t2.w) * iv2;
            a0 += BFLO(t3.x) * iv3; a1 += BFHI(t3.x) * iv3;
            a2 += BFLO(t3.y) * iv3; a3 += BFHI(t3.y) * iv3;
            a4 += BFLO(t3.z) * iv3; a5 += BFHI(t3.z) * iv3;
            a6 += BFLO(t3.w) * iv3; a7 += BFHI(t3.w) * iv3;
            a0 += BFLO(t4.x) * iv4; a1 += BFHI(t4.x) * iv4;
            a2 += BFLO(t4.y) * iv4; a3 += BFHI(t4.y) * iv4;
            a4 += BFLO(t4.z) * iv4; a5 += BFHI(t4.z) * iv4;
            a6 += BFLO(t4.w) * iv4; a7 += BFHI(t4.w) * iv4;
        }
        for (; i < i1; ++i) {                           // tail edges
            unsigned c1 = sortedc[i];
            const uint4 t1 = *(const uint4*)(TbRel +
                ((size_t)(c1 & 3u) * VOCAB + (c1 >> 8)) * DIM + sl * 8);
            float iv1 = inv_sh[c1 & 0xFFu];
            a0 += BFLO(t1.x) * iv1; a1 += BFHI(t1.x) * iv1;
            a2 += BFLO(t1.y) * iv1; a3 += BFHI(t1.y) * iv1;
            a4 += BFLO(t1.z) * iv1; a5 += BFHI(t1.z) * iv1;
            a6 += BFLO(t1.w) * iv1; a7 += BFHI(t1.w) * iv1;
        }
        // root + bias + ReLU -> LDS rows
        int xv = x[node];
        const uint4 rt = *(const uint4*)(Tb + (size_t)xv * DIM + sl * 8);
        const float4 b0 = *(const float4*)(bias + sl * 8);
        const float4 b1 = *(const float4*)(bias + sl * 8 + 4);
        float* rp = rows + n * DIM + sl * 8;
        rp[0] = fmaxf(BFLO(rt.x) + b0.x + a0, 0.f);
        rp[1] = fmaxf(BFHI(rt.x) + b0.y + a1, 0.f);
        rp[2] = fmaxf(BFLO(rt.y) + b0.z + a2, 0.f);
        rp[3] = fmaxf(BFHI(rt.y) + b0.w + a3, 0.f);
        rp[4] = fmaxf(BFLO(rt.z) + b1.x + a4, 0.f);
        rp[5] = fmaxf(BFHI(rt.z) + b1.y + a5, 0.f);
        rp[6] = fmaxf(BFLO(rt.w) + b1.z + a6, 0.f);
        rp[7] = fmaxf(BFHI(rt.w) + b1.w + a7, 0.f);
    }
    __syncthreads();

    // phase 3: per-graph pooling reduce (batch sorted: few graphs/bucket).
    int gmin = batch_sh[0];
    int gmax = batch_sh[nvalid - 1];
    int f  = t & 63;                    // feature
    int n0 = t >> 6;                    // 4-thread stride over nodes
    for (int g = gmin; g <= gmax; ++g) {
        float a = 0.f;
        for (int n = n0; n < nvalid; n += 4)
            a += (batch_sh[n] == g) ? rows[n * DIM + f] : 0.f;
        red[t] = a;
        __syncthreads();
        if (t < 64) {
            float tot = red[t] + red[t + 64] + red[t + 128] + red[t + 192];
            if (tot != 0.f) atomicAdd(&g_sum[g * DIM + t], tot);
        }
        __syncthreads();
    }
}

// ---------------------------------------------------------------------------
// Kernel 5: per-graph mean + 64->2 linear. 512 blocks x 64 lanes.
__device__ __forceinline__ int lbound(const int* __restrict__ b, int val) {
    int lo = 0, hi = N_NODES;
    while (lo < hi) {
        int mid = (lo + hi) >> 1;
        if (b[mid] < val) lo = mid + 1; else hi = mid;
    }
    return lo;
}

__global__ __launch_bounds__(64)
void final_linear(const int* __restrict__ batch,
                  const float* __restrict__ g_sum,
                  const float* __restrict__ lin_W,
                  const float* __restrict__ lin_b,
                  float* __restrict__ out) {
    int g = blockIdx.x;
    int l = threadIdx.x;   // 0..63
    int s = lbound(batch, g);
    int e = lbound(batch, g + 1);
    float mean = (e > s) ? g_sum[g * DIM + l] / (float)(e - s) : 0.f;
    float p0 = mean * lin_W[l * 2 + 0];
    float p1 = mean * lin_W[l * 2 + 1];
#pragma unroll
    for (int off2 = 32; off2 > 0; off2 >>= 1) {
        p0 += __shfl_down(p0, off2, 64);
        p1 += __shfl_down(p1, off2, 64);
    }
    if (l == 0) {
        out[g * 2 + 0] = p0 + lin_b[0];
        out[g * 2 + 1] = p1 + lin_b[1];
    }
}

// ---------------------------------------------------------------------------
extern "C" void kernel_launch(void* const* d_in, const int* in_sizes, int n_in,
                              void* d_out, int out_size, void* d_ws, size_t ws_size,
                              hipStream_t stream) {
    const int*   x      = (const int*)d_in[0];
    const int*   eidx   = (const int*)d_in[1];   // [2, E]
    const int*   etype  = (const int*)d_in[2];
    const int*   batch  = (const int*)d_in[3];
    const float* embed  = (const float*)d_in[4];
    const float* W_rel  = (const float*)d_in[5];
    const float* W_root = (const float*)d_in[6];
    const float* bias   = (const float*)d_in[7];
    const float* lin_W  = (const float*)d_in[8];
    const float* lin_b  = (const float*)d_in[9];
    float* out = (float*)d_out;

    const int* src = eidx;
    const int* dst = eidx + N_EDGES;

    // Workspace layout (bytes). No memsets (g_sum zeroed in hist_build).
    //   Tb      : 4*VOCAB*64*2 = 5,120,000   at          0
    //   rec     : 1M*4         = 4,000,000   at  5,120,000
    //   payload : 1M*4         = 4,000,000   at  9,120,000
    //   loc     : NB*SB*4      = 1,531,740   at 13,120,000
    //   btot    : NB*4         =     6,252   at 14,651,776
    //   bbase   : (NB+1)*4     =     6,256   at 14,658,048
    //   bh      : NB*SB*4      = 1,531,740   at 14,664,320
    //   g_sum   : 512*64*4     =   131,072   at 16,196,096
    char* ws = (char*)d_ws;
    ushort_t* Tb      = (ushort_t*)(ws);
    unsigned* rec     = (unsigned*)(ws + 5120000);
    unsigned* payload = (unsigned*)(ws + 9120000);
    int* loc          = (int*)(ws + 13120000);
    int* btot         = (int*)(ws + 14651776);
    int* bbase        = (int*)(ws + 14658048);
    int* bh           = (int*)(ws + 14664320);
    float* g_sum      = (float*)(ws + 16196096);

    // 1. fused: bucket histogram + payload (+g_sum zero)  ||  bf16 table build
    hist_build<<<SB + BUILD_BLOCKS, 256, 0, stream>>>(
        src, dst, etype, x, bh, payload, g_sum, embed, W_rel, W_root, Tb);

    // 2. per-bucket row scan -> loc, btot
    rowscan<<<NB, 256, 0, stream>>>(bh, loc, btot);

    // 3. bucket scatter with inline btot scan (block 0 publishes bbase)
    bucket_scatter<<<SB, 1024, 0, stream>>>(dst, payload, loc, btot, bbase, rec);

    // 4. fused LDS sort + aggregation + pooling
    sort_aggregate<<<NB, 256, 0, stream>>>(x, batch, bbase, rec, Tb, bias, g_sum);

    // 5. per-graph mean + linear
    final_linear<<<N_GRAPHS, 64, 0, stream>>>(batch, g_sum, lin_W, lin_b, out);
}